// Round 1
// baseline (237.352 us; speedup 1.0000x reference)
//
#include <hip/hip_runtime.h>

// Problem constants
#define BATCH 2
#define SEQ   2048
#define NH    16
#define DK    64
#define DM    1024
#define MROWS 4096        // BATCH*SEQ
#define NX    4194304     // MROWS*DM elems
#define NW    1048576     // DM*DM elems

typedef __attribute__((ext_vector_type(8))) short bf16x8;
typedef __attribute__((ext_vector_type(4))) short bf16x4;
typedef __attribute__((ext_vector_type(4))) float f32x4;
typedef __attribute__((ext_vector_type(4))) unsigned short us16x4;
typedef __attribute__((ext_vector_type(2))) unsigned int u32x2;

// Device pass has the _1k builtin; host pass only needs to parse.
#if __has_builtin(__builtin_amdgcn_mfma_f32_16x16x16bf16_1k)
#define MFMA16(a, b, c) __builtin_amdgcn_mfma_f32_16x16x16bf16_1k(a, b, c, 0, 0, 0)
#else
#define MFMA16(a, b, c) (c)
#endif

__device__ __forceinline__ unsigned short f2bf(float f) {
  unsigned int u = __builtin_bit_cast(unsigned int, f);
  u += 0x7FFFu + ((u >> 16) & 1u);
  return (unsigned short)(u >> 16);
}

// pack two fp32 -> two truncated bf16 in one dword: {hi>>16 : lo>>16}
__device__ __forceinline__ unsigned int pkbf(float hi, float lo) {
#if __has_builtin(__builtin_amdgcn_perm)
  return __builtin_amdgcn_perm(__builtin_bit_cast(unsigned int, hi),
                               __builtin_bit_cast(unsigned int, lo), 0x07060302u);
#else
  return (__builtin_bit_cast(unsigned int, hi) & 0xffff0000u) |
         (__builtin_bit_cast(unsigned int, lo) >> 16);
#endif
}

__device__ __forceinline__ void g2l16(void* lds, const void* g) {
  __builtin_amdgcn_global_load_lds(
      (const __attribute__((address_space(1))) void*)g,
      (__attribute__((address_space(3))) void*)lds, 16, 0, 0);
}

// ---------------- cast fp32 -> bf16 (7 arrays concatenated) ----------------
__global__ __launch_bounds__(256) void cast_all(
    const float* __restrict__ q, const float* __restrict__ k, const float* __restrict__ v,
    const float* __restrict__ wq, const float* __restrict__ wk,
    const float* __restrict__ wv, const float* __restrict__ wo,
    unsigned short* __restrict__ dst) {
  size_t e = ((size_t)blockIdx.x * 256 + threadIdx.x) * 4;
  const float* src;
  if      (e < (size_t)NX)        src = q  + e;
  else if (e < (size_t)2*NX)      src = k  + (e - (size_t)NX);
  else if (e < (size_t)3*NX)      src = v  + (e - (size_t)2*NX);
  else if (e < (size_t)3*NX+NW)   src = wq + (e - (size_t)3*NX);
  else if (e < (size_t)3*NX+2*NW) src = wk + (e - (size_t)3*NX-NW);
  else if (e < (size_t)3*NX+3*NW) src = wv + (e - (size_t)3*NX-2*NW);
  else                            src = wo + (e - (size_t)3*NX-3*NW);
  float4 f = *(const float4*)src;
  us16x4 o;
  o[0] = f2bf(f.x); o[1] = f2bf(f.y); o[2] = f2bf(f.z); o[3] = f2bf(f.w);
  *(us16x4*)(dst + e) = o;
}

// ---------------- GEMM: C = X @ W^T (+bias), BMx128 tile, 1-deep pipeline ----------------
// MODE 0: z in {0,1,2}: z<2 -> bf16 scatter to [B,H,S,DK] (z==0 scaled);
//         z==2 -> V^T bf16 scatter to [B,H,DK,S] (packed us16x4 along s).
// MODE 1: fp32 output to d_out with bias.
// BM in {128, 64}; waves cover (BM/2 x 64) each in a 2x2 arrangement.
template <int MODE, int BM>
__global__ __launch_bounds__(256) void gemm_bt(
    const unsigned short* __restrict__ Xbase, const unsigned short* __restrict__ Wbase,
    const float* __restrict__ b0, const float* __restrict__ b1, const float* __restrict__ b2,
    unsigned short* __restrict__ qkv_dst, float* __restrict__ fout, float qscale) {
  constexpr int IM = BM / 32;           // 16-row frags per wave
  constexpr int ASHOTS = (BM * 32) / 2048;
  const int tid  = threadIdx.x;
  const int lane = tid & 63;
  const int w    = tid >> 6;
  const int wm   = w >> 1, wn = w & 1;
  const int x15  = lane & 15, quad = lane >> 4;
  const int row0 = blockIdx.x * BM;
  const int col0 = blockIdx.y * 128;
  const int z    = blockIdx.z;

  const unsigned short* A  = Xbase + (size_t)z * NX;
  const unsigned short* Wp = Wbase + (size_t)z * NW;
  const float* bias = (MODE == 0) ? (z == 0 ? b0 : (z == 1 ? b1 : b2)) : b0;
  const float zs = (MODE == 0 && z == 0) ? qscale : 1.0f;

  __shared__ __align__(16) unsigned short At[2][BM * 32];
  __shared__ __align__(16) unsigned short Bt[2][128 * 32];

  f32x4 acc[IM][4] = {};

  auto stage = [&](int buf, int kt) {
#pragma unroll
    for (int j = 0; j < ASHOTS; ++j) {
      int e = (j * 256 + tid) * 8;
      int r = e >> 5, c = e & 31;
      g2l16(&At[buf][e], A + (size_t)(row0 + r) * DM + kt + c);
    }
#pragma unroll
    for (int j = 0; j < 2; ++j) {
      int e = (j * 256 + tid) * 8;
      int r = e >> 5, c = e & 31;
      g2l16(&Bt[buf][e], Wp + (size_t)(col0 + r) * DM + kt + c);
    }
  };

  stage(0, 0);
  for (int it = 0; it < DM / 32; ++it) {
    const int cur = it & 1;
    __syncthreads();                 // drains prefetch issued last iter; guards buf reuse
    if (it + 1 < DM / 32) stage(cur ^ 1, (it + 1) * 32);
    bf16x8 af[IM], bfv[4];
#pragma unroll
    for (int i = 0; i < IM; ++i)
      af[i] = *(const bf16x8*)&At[cur][(wm * (BM / 2) + i * 16 + x15) * 32 + quad * 8];
#pragma unroll
    for (int jn = 0; jn < 4; ++jn)
      bfv[jn] = *(const bf16x8*)&Bt[cur][(wn * 64 + jn * 16 + x15) * 32 + quad * 8];
#pragma unroll
    for (int i = 0; i < IM; ++i)
#pragma unroll
      for (int jn = 0; jn < 4; ++jn)
        acc[i][jn] = __builtin_amdgcn_mfma_f32_16x16x32_bf16(af[i], bfv[jn], acc[i][jn], 0, 0, 0);
  }

  // epilogue: C[row=(quad*4+r), col=x15] within each 16x16 tile
#pragma unroll
  for (int jn = 0; jn < 4; ++jn) {
    const int n = col0 + wn * 64 + jn * 16 + x15;
    const float bv = bias[n];
#pragma unroll
    for (int i = 0; i < IM; ++i) {
      const int m0 = row0 + wm * (BM / 2) + i * 16 + quad * 4;
      if (MODE == 0 && z == 2) {
        us16x4 pk;
#pragma unroll
        for (int r = 0; r < 4; ++r) pk[r] = f2bf(acc[i][jn][r] + bv);
        const int b = m0 >> 11, s = m0 & 2047;
        const int h = n >> 6,  dk = n & 63;
        *(us16x4*)&qkv_dst[(size_t)2 * NX + (((size_t)(b * NH + h) * DK + dk) << 11) + s] = pk;
      } else {
#pragma unroll
        for (int r = 0; r < 4; ++r) {
          const int m = m0 + r;
          float val = (acc[i][jn][r] + bv) * zs;
          if (MODE == 0) {
            const int b = m >> 11, s = m & 2047;
            const int h = n >> 6,  dk = n & 63;
            qkv_dst[(size_t)z * NX + (((size_t)(b * NH + h) * SEQ + s) << 6) + dk] = f2bf(val);
          } else {
            fout[(size_t)m * DM + n] = val;
          }
        }
      }
    }
  }
}

// ---------------- flash attention, q-tile 128, 1-deep pipelined K/V staging ----------------
// Wave owns 32 q-rows (two 16-row fragment groups) so every K/V LDS read is
// amortized over 2x the MFMA work -- the kernel was LDS-pipe-bound at 16 rows.
// S^T via mfma(A=K,B=Q); P stays in registers (C-layout == B-frag of 16x16x16);
// O^T = V^T P^T. Fixed-max softmax; l via ones-row MFMA. All kf ds_reads issued
// at tile top (latency overlap).
__global__ __launch_bounds__(256) void attn(
    const unsigned short* __restrict__ Qb, const unsigned short* __restrict__ Kb,
    const unsigned short* __restrict__ VTb, unsigned short* __restrict__ AO) {
  const int tid  = threadIdx.x;
  const int lane = tid & 63;
  const int w    = tid >> 6;
  const int x15  = lane & 15, quad = lane >> 4;
  const int qt = blockIdx.x;   // 16
  const int h  = blockIdx.y;   // 16
  const int b  = blockIdx.z;   // 2
  const size_t bh = ((size_t)(b * NH + h)) * SEQ * DK;
  const unsigned short* Q  = Qb  + bh;
  const unsigned short* K  = Kb  + bh;
  const unsigned short* VT = VTb + bh;   // [64 d][2048 s]
  const int q0 = qt * 128 + w * 32;      // wave covers q0 .. q0+31

  __shared__ __align__(16) unsigned short Kl[2][64 * 64];  // swizzled, 8 KB each
  __shared__ __align__(16) unsigned short Vl[2][64 * 64];

  // Q fragments (scaled by 1/8*log2e at projection): two 16-row groups
  bf16x8 qf[2][2];
#pragma unroll
  for (int qg = 0; qg < 2; ++qg)
#pragma unroll
    for (int ks = 0; ks < 2; ++ks)
      qf[qg][ks] = *(const bf16x8*)&Q[(size_t)(q0 + qg * 16 + x15) * DK + ks * 32 + quad * 8];

  f32x4 po[2][4] = {};
  f32x4 pol[2] = {};
  const bf16x4 vone = {(short)0x3F80, (short)0x3F80, (short)0x3F80, (short)0x3F80};

  // staging maps (swizzled): K slot(s,dg)=s*8+(dg^(s&7)); V slot(d,sg)=d*8+(sg^(d&7))
  const int sK0 = tid >> 3,          sK1 = (tid + 256) >> 3;
  const int dgK0 = (tid & 7) ^ (sK0 & 7), dgK1 = (tid & 7) ^ (sK1 & 7);

  auto stageKV = [&](int buf, int s0) {
    g2l16(&Kl[buf][(size_t)tid * 8],         K + (size_t)(s0 + sK0) * DK + dgK0 * 8);
    g2l16(&Kl[buf][(size_t)(tid + 256) * 8], K + (size_t)(s0 + sK1) * DK + dgK1 * 8);
    g2l16(&Vl[buf][(size_t)tid * 8],         VT + (size_t)sK0 * SEQ + s0 + dgK0 * 8);
    g2l16(&Vl[buf][(size_t)(tid + 256) * 8], VT + (size_t)sK1 * SEQ + s0 + dgK1 * 8);
  };

  stageKV(0, 0);
  for (int s0 = 0; s0 < SEQ; s0 += 64) {
    const int cur = (s0 >> 6) & 1;
    __syncthreads();                 // drains last iter's prefetch; guards buf reuse
    if (s0 + 64 < SEQ) stageKV(cur ^ 1, s0 + 64);

    // issue all K-fragment reads up front (latency overlaps sh-loop compute)
    bf16x8 kf[4][2];
#pragma unroll
    for (int sh = 0; sh < 4; ++sh) {
      const int kbase = (sh * 16 + x15) * 8;
      kf[sh][0] = *(const bf16x8*)&Kl[cur][(kbase + ((0 + quad) ^ (x15 & 7))) * 8];
      kf[sh][1] = *(const bf16x8*)&Kl[cur][(kbase + ((4 + quad) ^ (x15 & 7))) * 8];
    }

#pragma unroll
    for (int sh = 0; sh < 4; ++sh) {
      bf16x4 pf[2];
#pragma unroll
      for (int qg = 0; qg < 2; ++qg) {
        f32x4 sacc = {};
        sacc = __builtin_amdgcn_mfma_f32_16x16x32_bf16(kf[sh][0], qf[qg][0], sacc, 0, 0, 0);
        sacc = __builtin_amdgcn_mfma_f32_16x16x32_bf16(kf[sh][1], qf[qg][1], sacc, 0, 0, 0);
        float p0 = __builtin_amdgcn_exp2f(sacc[0]);
        float p1 = __builtin_amdgcn_exp2f(sacc[1]);
        float p2 = __builtin_amdgcn_exp2f(sacc[2]);
        float p3 = __builtin_amdgcn_exp2f(sacc[3]);
        u32x2 uu;
        uu[0] = pkbf(p1, p0);
        uu[1] = pkbf(p3, p2);
        pf[qg] = __builtin_bit_cast(bf16x4, uu);
        pol[qg] = MFMA16(vone, pf[qg], pol[qg]);   // l[q] accumulates in C
      }

#pragma unroll
      for (int nt = 0; nt < 4; ++nt) {
        const int d = nt * 16 + x15;
        const int sg = (sh * 2 + (quad >> 1)) ^ (d & 7);
        bf16x4 vf = *(const bf16x4*)&Vl[cur][(d * 8 + sg) * 8 + (quad & 1) * 4];
        po[0][nt] = MFMA16(vf, pf[0], po[0][nt]);  // one LDS read feeds both q-groups
        po[1][nt] = MFMA16(vf, pf[1], po[1][nt]);
      }
    }
  }

  // epilogue: O^T C-layout: col=x15 -> q, row=quad*4+r -> d (within nt*16)
#pragma unroll
  for (int qg = 0; qg < 2; ++qg) {
    const float inv = 1.0f / pol[qg][0];   // all 4 regs identical (ones-row)
    const int s = q0 + qg * 16 + x15;
#pragma unroll
    for (int nt = 0; nt < 4; ++nt) {
      us16x4 pk;
#pragma unroll
      for (int r = 0; r < 4; ++r) pk[r] = f2bf(po[qg][nt][r] * inv);
      const int d = nt * 16 + quad * 4;
      *(us16x4*)&AO[((size_t)(b * SEQ + s)) * DM + h * DK + d] = pk;
    }
  }
}

extern "C" void kernel_launch(void* const* d_in, const int* in_sizes, int n_in,
                              void* d_out, int out_size, void* d_ws, size_t ws_size,
                              hipStream_t stream) {
  const float* q  = (const float*)d_in[0];
  const float* k  = (const float*)d_in[1];
  const float* v  = (const float*)d_in[2];
  const float* wq = (const float*)d_in[3];
  const float* bq = (const float*)d_in[4];
  const float* wk = (const float*)d_in[5];
  const float* bk = (const float*)d_in[6];
  const float* wv = (const float*)d_in[7];
  const float* bv = (const float*)d_in[8];
  const float* wo = (const float*)d_in[9];
  const float* bo = (const float*)d_in[10];
  float* out = (float*)d_out;

  unsigned short* ws = (unsigned short*)d_ws;
  unsigned short* Xq = ws;                               // 3*NX of X
  unsigned short* Wb = ws + (size_t)3 * NX;              // 4*NW of W
  unsigned short* Qb = ws + (size_t)3 * NX + 4 * NW;     // Q,K [B,H,S,DK]; V^T [B,H,DK,S]
  unsigned short* AO = Qb + (size_t)3 * NX;              // NX attn out

  // scale folded into Q: (1/sqrt(DK)) * log2(e)
  const float qscale = 0.125f * 1.4426950408889634f;

  cast_all<<<16384, 256, 0, stream>>>(q, k, v, wq, wk, wv, wo, ws);
  gemm_bt<0, 128><<<dim3(32, 8, 3), 256, 0, stream>>>(Xq, Wb, bq, bk, bv, Qb, nullptr, qscale);
  attn<<<dim3(16, 16, 2), 256, 0, stream>>>(Qb, Qb + (size_t)NX, Qb + (size_t)2 * NX, AO);
  gemm_bt<1, 64><<<dim3(64, 8, 1), 256, 0, stream>>>(AO, Wb + (size_t)3 * NW, bo, bo, bo,
                                                     nullptr, out, 1.0f);
}

// Round 2
// 223.910 us; speedup vs baseline: 1.0600x; 1.0600x over previous
//
#include <hip/hip_runtime.h>

// Problem constants
#define BATCH 2
#define SEQ   2048
#define NH    16
#define DK    64
#define DM    1024
#define MROWS 4096        // BATCH*SEQ
#define NX    4194304     // MROWS*DM elems
#define NW    1048576     // DM*DM elems

typedef __attribute__((ext_vector_type(8))) short bf16x8;
typedef __attribute__((ext_vector_type(4))) short bf16x4;
typedef __attribute__((ext_vector_type(4))) float f32x4;
typedef __attribute__((ext_vector_type(4))) unsigned short us16x4;
typedef __attribute__((ext_vector_type(2))) unsigned int u32x2;

// Device pass has the _1k builtin; host pass only needs to parse.
#if __has_builtin(__builtin_amdgcn_mfma_f32_16x16x16bf16_1k)
#define MFMA16(a, b, c) __builtin_amdgcn_mfma_f32_16x16x16bf16_1k(a, b, c, 0, 0, 0)
#else
#define MFMA16(a, b, c) (c)
#endif

__device__ __forceinline__ unsigned short f2bf(float f) {
  unsigned int u = __builtin_bit_cast(unsigned int, f);
  u += 0x7FFFu + ((u >> 16) & 1u);
  return (unsigned short)(u >> 16);
}

// pack two fp32 -> two truncated bf16 in one dword: {hi>>16 : lo>>16}
__device__ __forceinline__ unsigned int pkbf(float hi, float lo) {
#if __has_builtin(__builtin_amdgcn_perm)
  return __builtin_amdgcn_perm(__builtin_bit_cast(unsigned int, hi),
                               __builtin_bit_cast(unsigned int, lo), 0x07060302u);
#else
  return (__builtin_bit_cast(unsigned int, hi) & 0xffff0000u) |
         (__builtin_bit_cast(unsigned int, lo) >> 16);
#endif
}

__device__ __forceinline__ void g2l16(void* lds, const void* g) {
  __builtin_amdgcn_global_load_lds(
      (const __attribute__((address_space(1))) void*)g,
      (__attribute__((address_space(3))) void*)lds, 16, 0, 0);
}

// ---------------- cast fp32 -> bf16 (7 arrays concatenated) ----------------
__global__ __launch_bounds__(256) void cast_all(
    const float* __restrict__ q, const float* __restrict__ k, const float* __restrict__ v,
    const float* __restrict__ wq, const float* __restrict__ wk,
    const float* __restrict__ wv, const float* __restrict__ wo,
    unsigned short* __restrict__ dst) {
  size_t e = ((size_t)blockIdx.x * 256 + threadIdx.x) * 4;
  const float* src;
  if      (e < (size_t)NX)        src = q  + e;
  else if (e < (size_t)2*NX)      src = k  + (e - (size_t)NX);
  else if (e < (size_t)3*NX)      src = v  + (e - (size_t)2*NX);
  else if (e < (size_t)3*NX+NW)   src = wq + (e - (size_t)3*NX);
  else if (e < (size_t)3*NX+2*NW) src = wk + (e - (size_t)3*NX-NW);
  else if (e < (size_t)3*NX+3*NW) src = wv + (e - (size_t)3*NX-2*NW);
  else                            src = wo + (e - (size_t)3*NX-3*NW);
  float4 f = *(const float4*)src;
  us16x4 o;
  o[0] = f2bf(f.x); o[1] = f2bf(f.y); o[2] = f2bf(f.z); o[3] = f2bf(f.w);
  *(us16x4*)(dst + e) = o;
}

// ---------------- GEMM: C = X @ W^T (+bias), BMx128 tile, 1-deep pipeline ----------------
// MODE 0: z in {0,1,2}: z<2 -> bf16 scatter to [B,H,S,DK] (z==0 scaled);
//         z==2 -> V^T bf16 scatter to [B,H,DK,S] (packed us16x4 along s).
// MODE 1: fp32 output to d_out with bias.
// BM in {128, 64}; waves cover (BM/2 x 64) each in a 2x2 arrangement.
template <int MODE, int BM>
__global__ __launch_bounds__(256) void gemm_bt(
    const unsigned short* __restrict__ Xbase, const unsigned short* __restrict__ Wbase,
    const float* __restrict__ b0, const float* __restrict__ b1, const float* __restrict__ b2,
    unsigned short* __restrict__ qkv_dst, float* __restrict__ fout, float qscale) {
  constexpr int IM = BM / 32;           // 16-row frags per wave
  constexpr int ASHOTS = (BM * 32) / 2048;
  const int tid  = threadIdx.x;
  const int lane = tid & 63;
  const int w    = tid >> 6;
  const int wm   = w >> 1, wn = w & 1;
  const int x15  = lane & 15, quad = lane >> 4;
  const int row0 = blockIdx.x * BM;
  const int col0 = blockIdx.y * 128;
  const int z    = blockIdx.z;

  const unsigned short* A  = Xbase + (size_t)z * NX;
  const unsigned short* Wp = Wbase + (size_t)z * NW;
  const float* bias = (MODE == 0) ? (z == 0 ? b0 : (z == 1 ? b1 : b2)) : b0;
  const float zs = (MODE == 0 && z == 0) ? qscale : 1.0f;

  __shared__ __align__(16) unsigned short At[2][BM * 32];
  __shared__ __align__(16) unsigned short Bt[2][128 * 32];

  f32x4 acc[IM][4] = {};

  auto stage = [&](int buf, int kt) {
#pragma unroll
    for (int j = 0; j < ASHOTS; ++j) {
      int e = (j * 256 + tid) * 8;
      int r = e >> 5, c = e & 31;
      g2l16(&At[buf][e], A + (size_t)(row0 + r) * DM + kt + c);
    }
#pragma unroll
    for (int j = 0; j < 2; ++j) {
      int e = (j * 256 + tid) * 8;
      int r = e >> 5, c = e & 31;
      g2l16(&Bt[buf][e], Wp + (size_t)(col0 + r) * DM + kt + c);
    }
  };

  stage(0, 0);
  for (int it = 0; it < DM / 32; ++it) {
    const int cur = it & 1;
    __syncthreads();                 // drains prefetch issued last iter; guards buf reuse
    if (it + 1 < DM / 32) stage(cur ^ 1, (it + 1) * 32);
    bf16x8 af[IM], bfv[4];
#pragma unroll
    for (int i = 0; i < IM; ++i)
      af[i] = *(const bf16x8*)&At[cur][(wm * (BM / 2) + i * 16 + x15) * 32 + quad * 8];
#pragma unroll
    for (int jn = 0; jn < 4; ++jn)
      bfv[jn] = *(const bf16x8*)&Bt[cur][(wn * 64 + jn * 16 + x15) * 32 + quad * 8];
#pragma unroll
    for (int i = 0; i < IM; ++i)
#pragma unroll
      for (int jn = 0; jn < 4; ++jn)
        acc[i][jn] = __builtin_amdgcn_mfma_f32_16x16x32_bf16(af[i], bfv[jn], acc[i][jn], 0, 0, 0);
  }

  // epilogue: C[row=(quad*4+r), col=x15] within each 16x16 tile
#pragma unroll
  for (int jn = 0; jn < 4; ++jn) {
    const int n = col0 + wn * 64 + jn * 16 + x15;
    const float bv = bias[n];
#pragma unroll
    for (int i = 0; i < IM; ++i) {
      const int m0 = row0 + wm * (BM / 2) + i * 16 + quad * 4;
      if (MODE == 0 && z == 2) {
        us16x4 pk;
#pragma unroll
        for (int r = 0; r < 4; ++r) pk[r] = f2bf(acc[i][jn][r] + bv);
        const int b = m0 >> 11, s = m0 & 2047;
        const int h = n >> 6,  dk = n & 63;
        *(us16x4*)&qkv_dst[(size_t)2 * NX + (((size_t)(b * NH + h) * DK + dk) << 11) + s] = pk;
      } else {
#pragma unroll
        for (int r = 0; r < 4; ++r) {
          const int m = m0 + r;
          float val = (acc[i][jn][r] + bv) * zs;
          if (MODE == 0) {
            const int b = m >> 11, s = m & 2047;
            const int h = n >> 6,  dk = n & 63;
            qkv_dst[(size_t)z * NX + (((size_t)(b * NH + h) * SEQ + s) << 6) + dk] = f2bf(val);
          } else {
            fout[(size_t)m * DM + n] = val;
          }
        }
      }
    }
  }
}

// ---------------- flash attention, q-tile 128, 1-deep pipelined K/V staging ----------------
// Wave owns 32 q-rows (two 16-row fragment groups). Grid-limited to 2 blocks/CU,
// so __launch_bounds__(256,2) tells the compiler to use the full 256-VGPR budget:
// kf/vf/qf live in registers, all LDS reads hoisted to the iteration top so their
// latency pipelines (the R1 kernel at 56 VGPRs serialized ds_read->MFMA chains).
// XCD swizzle: 512 blocks = 8 XCDs x 64; each XCD owns 4 (b,h) pairs -> 2 MB K/V
// working set resident in its 4 MB L2 -> staging hits local L2 (~200 cyc).
// S^T via mfma(A=K,B=Q); P stays in registers; O^T = V^T P^T. Fixed-max softmax;
// l via ones-row MFMA.
__global__ __launch_bounds__(256, 2) void attn(
    const unsigned short* __restrict__ Qb, const unsigned short* __restrict__ Kb,
    const unsigned short* __restrict__ VTb, unsigned short* __restrict__ AO) {
  const int tid  = threadIdx.x;
  const int lane = tid & 63;
  const int w    = tid >> 6;
  const int x15  = lane & 15, quad = lane >> 4;
  // bijective XCD swizzle: dispatch slot lin -> XCD lin&7; give each XCD a
  // contiguous 64-block chunk (= 4 (b,h) pairs sharing K/V in its L2)
  const int lin = (int)(blockIdx.x | (blockIdx.y << 4) | (blockIdx.z << 8));
  const int swz = ((lin & 7) << 6) | (lin >> 3);
  const int qt = swz & 15;          // 16
  const int h  = (swz >> 4) & 15;   // 16
  const int b  = swz >> 8;          // 2
  const size_t bh = ((size_t)(b * NH + h)) * SEQ * DK;
  const unsigned short* Q  = Qb  + bh;
  const unsigned short* K  = Kb  + bh;
  const unsigned short* VT = VTb + bh;   // [64 d][2048 s]
  const int q0 = qt * 128 + w * 32;      // wave covers q0 .. q0+31

  __shared__ __align__(16) unsigned short Kl[2][64 * 64];  // swizzled, 8 KB each
  __shared__ __align__(16) unsigned short Vl[2][64 * 64];

  // Q fragments (scaled by 1/8*log2e at projection): two 16-row groups
  bf16x8 qf[2][2];
#pragma unroll
  for (int qg = 0; qg < 2; ++qg)
#pragma unroll
    for (int ks = 0; ks < 2; ++ks)
      qf[qg][ks] = *(const bf16x8*)&Q[(size_t)(q0 + qg * 16 + x15) * DK + ks * 32 + quad * 8];

  f32x4 po[2][4] = {};
  f32x4 pol[2] = {};
  const bf16x4 vone = {(short)0x3F80, (short)0x3F80, (short)0x3F80, (short)0x3F80};

  // staging maps (swizzled): K slot(s,dg)=s*8+(dg^(s&7)); V slot(d,sg)=d*8+(sg^(d&7))
  const int sK0 = tid >> 3,          sK1 = (tid + 256) >> 3;
  const int dgK0 = (tid & 7) ^ (sK0 & 7), dgK1 = (tid & 7) ^ (sK1 & 7);

  auto stageKV = [&](int buf, int s0) {
    g2l16(&Kl[buf][(size_t)tid * 8],         K + (size_t)(s0 + sK0) * DK + dgK0 * 8);
    g2l16(&Kl[buf][(size_t)(tid + 256) * 8], K + (size_t)(s0 + sK1) * DK + dgK1 * 8);
    g2l16(&Vl[buf][(size_t)tid * 8],         VT + (size_t)sK0 * SEQ + s0 + dgK0 * 8);
    g2l16(&Vl[buf][(size_t)(tid + 256) * 8], VT + (size_t)sK1 * SEQ + s0 + dgK1 * 8);
  };

  stageKV(0, 0);
  for (int s0 = 0; s0 < SEQ; s0 += 64) {
    const int cur = (s0 >> 6) & 1;
    __syncthreads();                 // drains last iter's prefetch; guards buf reuse
    if (s0 + 64 < SEQ) stageKV(cur ^ 1, s0 + 64);

    // issue ALL LDS reads for this tile up front: 8x b128 (K) + 16x b64 (V).
    // Latencies pipeline; compute body below is pure-register.
    bf16x8 kf[4][2];
#pragma unroll
    for (int sh = 0; sh < 4; ++sh) {
      const int kbase = (sh * 16 + x15) * 8;
      kf[sh][0] = *(const bf16x8*)&Kl[cur][(kbase + ((0 + quad) ^ (x15 & 7))) * 8];
      kf[sh][1] = *(const bf16x8*)&Kl[cur][(kbase + ((4 + quad) ^ (x15 & 7))) * 8];
    }
    bf16x4 vf[4][4];
#pragma unroll
    for (int sh = 0; sh < 4; ++sh)
#pragma unroll
      for (int nt = 0; nt < 4; ++nt) {
        const int d = nt * 16 + x15;
        const int sg = (sh * 2 + (quad >> 1)) ^ (d & 7);
        vf[sh][nt] = *(const bf16x4*)&Vl[cur][(d * 8 + sg) * 8 + (quad & 1) * 4];
      }

#pragma unroll
    for (int sh = 0; sh < 4; ++sh) {
      bf16x4 pf[2];
#pragma unroll
      for (int qg = 0; qg < 2; ++qg) {
        f32x4 sacc = {};
        sacc = __builtin_amdgcn_mfma_f32_16x16x32_bf16(kf[sh][0], qf[qg][0], sacc, 0, 0, 0);
        sacc = __builtin_amdgcn_mfma_f32_16x16x32_bf16(kf[sh][1], qf[qg][1], sacc, 0, 0, 0);
        float p0 = __builtin_amdgcn_exp2f(sacc[0]);
        float p1 = __builtin_amdgcn_exp2f(sacc[1]);
        float p2 = __builtin_amdgcn_exp2f(sacc[2]);
        float p3 = __builtin_amdgcn_exp2f(sacc[3]);
        u32x2 uu;
        uu[0] = pkbf(p1, p0);
        uu[1] = pkbf(p3, p2);
        pf[qg] = __builtin_bit_cast(bf16x4, uu);
        pol[qg] = MFMA16(vone, pf[qg], pol[qg]);   // l[q] accumulates in C
      }

#pragma unroll
      for (int nt = 0; nt < 4; ++nt) {
        po[0][nt] = MFMA16(vf[sh][nt], pf[0], po[0][nt]);  // one LDS read feeds both q-groups
        po[1][nt] = MFMA16(vf[sh][nt], pf[1], po[1][nt]);
      }
    }
  }

  // epilogue: O^T C-layout: col=x15 -> q, row=quad*4+r -> d (within nt*16)
#pragma unroll
  for (int qg = 0; qg < 2; ++qg) {
    const float inv = 1.0f / pol[qg][0];   // all 4 regs identical (ones-row)
    const int s = q0 + qg * 16 + x15;
#pragma unroll
    for (int nt = 0; nt < 4; ++nt) {
      us16x4 pk;
#pragma unroll
      for (int r = 0; r < 4; ++r) pk[r] = f2bf(po[qg][nt][r] * inv);
      const int d = nt * 16 + quad * 4;
      *(us16x4*)&AO[((size_t)(b * SEQ + s)) * DM + h * DK + d] = pk;
    }
  }
}

extern "C" void kernel_launch(void* const* d_in, const int* in_sizes, int n_in,
                              void* d_out, int out_size, void* d_ws, size_t ws_size,
                              hipStream_t stream) {
  const float* q  = (const float*)d_in[0];
  const float* k  = (const float*)d_in[1];
  const float* v  = (const float*)d_in[2];
  const float* wq = (const float*)d_in[3];
  const float* bq = (const float*)d_in[4];
  const float* wk = (const float*)d_in[5];
  const float* bk = (const float*)d_in[6];
  const float* wv = (const float*)d_in[7];
  const float* bv = (const float*)d_in[8];
  const float* wo = (const float*)d_in[9];
  const float* bo = (const float*)d_in[10];
  float* out = (float*)d_out;

  unsigned short* ws = (unsigned short*)d_ws;
  unsigned short* Xq = ws;                               // 3*NX of X
  unsigned short* Wb = ws + (size_t)3 * NX;              // 4*NW of W
  unsigned short* Qb = ws + (size_t)3 * NX + 4 * NW;     // Q,K [B,H,S,DK]; V^T [B,H,DK,S]
  unsigned short* AO = Qb + (size_t)3 * NX;              // NX attn out

  // scale folded into Q: (1/sqrt(DK)) * log2(e)
  const float qscale = 0.125f * 1.4426950408889634f;

  cast_all<<<16384, 256, 0, stream>>>(q, k, v, wq, wk, wv, wo, ws);
  gemm_bt<0, 128><<<dim3(32, 8, 3), 256, 0, stream>>>(Xq, Wb, bq, bk, bv, Qb, nullptr, qscale);
  attn<<<dim3(16, 16, 2), 256, 0, stream>>>(Qb, Qb + (size_t)NX, Qb + (size_t)2 * NX, AO);
  gemm_bt<1, 64><<<dim3(64, 8, 1), 256, 0, stream>>>(AO, Wb + (size_t)3 * NW, bo, bo, bo,
                                                     nullptr, out, 1.0f);
}

// Round 3
// 220.041 us; speedup vs baseline: 1.0787x; 1.0176x over previous
//
#include <hip/hip_runtime.h>

// Problem constants
#define BATCH 2
#define SEQ   2048
#define NH    16
#define DK    64
#define DM    1024
#define MROWS 4096        // BATCH*SEQ
#define NX    4194304     // MROWS*DM elems
#define NW    1048576     // DM*DM elems

typedef __attribute__((ext_vector_type(8))) short bf16x8;
typedef __attribute__((ext_vector_type(4))) short bf16x4;
typedef __attribute__((ext_vector_type(4))) float f32x4;
typedef __attribute__((ext_vector_type(4))) unsigned short us16x4;
typedef __attribute__((ext_vector_type(2))) unsigned int u32x2;

// Device pass has the _1k builtin; host pass only needs to parse.
#if __has_builtin(__builtin_amdgcn_mfma_f32_16x16x16bf16_1k)
#define MFMA16(a, b, c) __builtin_amdgcn_mfma_f32_16x16x16bf16_1k(a, b, c, 0, 0, 0)
#else
#define MFMA16(a, b, c) (c)
#endif

__device__ __forceinline__ unsigned short f2bf(float f) {
  unsigned int u = __builtin_bit_cast(unsigned int, f);
  u += 0x7FFFu + ((u >> 16) & 1u);
  return (unsigned short)(u >> 16);
}

// pack two fp32 -> two truncated bf16 in one dword: {hi>>16 : lo>>16}
__device__ __forceinline__ unsigned int pkbf(float hi, float lo) {
#if __has_builtin(__builtin_amdgcn_perm)
  return __builtin_amdgcn_perm(__builtin_bit_cast(unsigned int, hi),
                               __builtin_bit_cast(unsigned int, lo), 0x07060302u);
#else
  return (__builtin_bit_cast(unsigned int, hi) & 0xffff0000u) |
         (__builtin_bit_cast(unsigned int, lo) >> 16);
#endif
}

__device__ __forceinline__ void g2l16(void* lds, const void* g) {
  __builtin_amdgcn_global_load_lds(
      (const __attribute__((address_space(1))) void*)g,
      (__attribute__((address_space(3))) void*)lds, 16, 0, 0);
}

// ---------------- cast fp32 -> bf16 (7 arrays concatenated) ----------------
__global__ __launch_bounds__(256) void cast_all(
    const float* __restrict__ q, const float* __restrict__ k, const float* __restrict__ v,
    const float* __restrict__ wq, const float* __restrict__ wk,
    const float* __restrict__ wv, const float* __restrict__ wo,
    unsigned short* __restrict__ dst) {
  size_t e = ((size_t)blockIdx.x * 256 + threadIdx.x) * 4;
  const float* src;
  if      (e < (size_t)NX)        src = q  + e;
  else if (e < (size_t)2*NX)      src = k  + (e - (size_t)NX);
  else if (e < (size_t)3*NX)      src = v  + (e - (size_t)2*NX);
  else if (e < (size_t)3*NX+NW)   src = wq + (e - (size_t)3*NX);
  else if (e < (size_t)3*NX+2*NW) src = wk + (e - (size_t)3*NX-NW);
  else if (e < (size_t)3*NX+3*NW) src = wv + (e - (size_t)3*NX-2*NW);
  else                            src = wo + (e - (size_t)3*NX-3*NW);
  float4 f = *(const float4*)src;
  us16x4 o;
  o[0] = f2bf(f.x); o[1] = f2bf(f.y); o[2] = f2bf(f.z); o[3] = f2bf(f.w);
  *(us16x4*)(dst + e) = o;
}

// ---------------- GEMM: C = X @ W^T (+bias), BMx128 tile, 1-deep pipeline ----------------
// MODE 0: z in {0,1,2}: z<2 -> bf16 scatter to [B,H,S,DK] (z==0 scaled);
//         z==2 -> V^T bf16 scatter to [B,H,DK,S] (packed us16x4 along s).
// MODE 1: fp32 output to d_out with bias.
// BM in {128, 64}; waves cover (BM/2 x 64) each in a 2x2 arrangement.
template <int MODE, int BM>
__global__ __launch_bounds__(256) void gemm_bt(
    const unsigned short* __restrict__ Xbase, const unsigned short* __restrict__ Wbase,
    const float* __restrict__ b0, const float* __restrict__ b1, const float* __restrict__ b2,
    unsigned short* __restrict__ qkv_dst, float* __restrict__ fout, float qscale) {
  constexpr int IM = BM / 32;           // 16-row frags per wave
  constexpr int ASHOTS = (BM * 32) / 2048;
  const int tid  = threadIdx.x;
  const int lane = tid & 63;
  const int w    = tid >> 6;
  const int wm   = w >> 1, wn = w & 1;
  const int x15  = lane & 15, quad = lane >> 4;
  const int row0 = blockIdx.x * BM;
  const int col0 = blockIdx.y * 128;
  const int z    = blockIdx.z;

  const unsigned short* A  = Xbase + (size_t)z * NX;
  const unsigned short* Wp = Wbase + (size_t)z * NW;
  const float* bias = (MODE == 0) ? (z == 0 ? b0 : (z == 1 ? b1 : b2)) : b0;
  const float zs = (MODE == 0 && z == 0) ? qscale : 1.0f;

  __shared__ __align__(16) unsigned short At[2][BM * 32];
  __shared__ __align__(16) unsigned short Bt[2][128 * 32];

  f32x4 acc[IM][4] = {};

  auto stage = [&](int buf, int kt) {
#pragma unroll
    for (int j = 0; j < ASHOTS; ++j) {
      int e = (j * 256 + tid) * 8;
      int r = e >> 5, c = e & 31;
      g2l16(&At[buf][e], A + (size_t)(row0 + r) * DM + kt + c);
    }
#pragma unroll
    for (int j = 0; j < 2; ++j) {
      int e = (j * 256 + tid) * 8;
      int r = e >> 5, c = e & 31;
      g2l16(&Bt[buf][e], Wp + (size_t)(col0 + r) * DM + kt + c);
    }
  };

  stage(0, 0);
  for (int it = 0; it < DM / 32; ++it) {
    const int cur = it & 1;
    __syncthreads();                 // drains prefetch issued last iter; guards buf reuse
    if (it + 1 < DM / 32) stage(cur ^ 1, (it + 1) * 32);
    bf16x8 af[IM], bfv[4];
#pragma unroll
    for (int i = 0; i < IM; ++i)
      af[i] = *(const bf16x8*)&At[cur][(wm * (BM / 2) + i * 16 + x15) * 32 + quad * 8];
#pragma unroll
    for (int jn = 0; jn < 4; ++jn)
      bfv[jn] = *(const bf16x8*)&Bt[cur][(wn * 64 + jn * 16 + x15) * 32 + quad * 8];
#pragma unroll
    for (int i = 0; i < IM; ++i)
#pragma unroll
      for (int jn = 0; jn < 4; ++jn)
        acc[i][jn] = __builtin_amdgcn_mfma_f32_16x16x32_bf16(af[i], bfv[jn], acc[i][jn], 0, 0, 0);
  }

  // epilogue: C[row=(quad*4+r), col=x15] within each 16x16 tile
#pragma unroll
  for (int jn = 0; jn < 4; ++jn) {
    const int n = col0 + wn * 64 + jn * 16 + x15;
    const float bv = bias[n];
#pragma unroll
    for (int i = 0; i < IM; ++i) {
      const int m0 = row0 + wm * (BM / 2) + i * 16 + quad * 4;
      if (MODE == 0 && z == 2) {
        us16x4 pk;
#pragma unroll
        for (int r = 0; r < 4; ++r) pk[r] = f2bf(acc[i][jn][r] + bv);
        const int b = m0 >> 11, s = m0 & 2047;
        const int h = n >> 6,  dk = n & 63;
        *(us16x4*)&qkv_dst[(size_t)2 * NX + (((size_t)(b * NH + h) * DK + dk) << 11) + s] = pk;
      } else {
#pragma unroll
        for (int r = 0; r < 4; ++r) {
          const int m = m0 + r;
          float val = (acc[i][jn][r] + bv) * zs;
          if (MODE == 0) {
            const int b = m >> 11, s = m & 2047;
            const int h = n >> 6,  dk = n & 63;
            qkv_dst[(size_t)z * NX + (((size_t)(b * NH + h) * SEQ + s) << 6) + dk] = f2bf(val);
          } else {
            fout[(size_t)m * DM + n] = val;
          }
        }
      }
    }
  }
}

// ---------------- flash attention, q-tile 128, 2x2 wave split ----------------
// R2 finding: kf/vf LDS reads were identical across the 4 waves (4x redundant)
// and the LDS pipe was the largest per-iter consumer. Split: wave (wq,ws) owns
// q-half wq*64..+63 AND s-half ws*32..+31 of each 64-wide K/V tile -> each wave
// reads only its 2 sh-slices (4x b128 K + 8x b64 V, half the prior traffic);
// MFMA/exp2 totals conserved (2sh x 4qg == 4sh x 2qg). l-row-sum moved from
// ones-row MFMA to 4 VALU adds/group (frees the matrix pipe); cross-quad and
// cross-ws reduction of O,l happens once in the epilogue via an LDS buffer that
// overlays Kl/Vl (stride 68 floats to keep b128 rows conflict-light).
// setprio(1) around the compute cluster (T5). XCD swizzle as in R2.
__global__ __launch_bounds__(256, 2) void attn(
    const unsigned short* __restrict__ Qb, const unsigned short* __restrict__ Kb,
    const unsigned short* __restrict__ VTb, unsigned short* __restrict__ AO) {
  const int tid  = threadIdx.x;
  const int lane = tid & 63;
  const int w    = tid >> 6;
  const int wq   = w & 1;        // q-half owner
  const int ws   = w >> 1;       // s-half owner
  const int x15  = lane & 15, quad = lane >> 4;
  // bijective XCD swizzle: 512 blocks = 8 XCDs x 64; each XCD owns 4 (b,h)
  const int lin = (int)(blockIdx.x | (blockIdx.y << 4) | (blockIdx.z << 8));
  const int swz = ((lin & 7) << 6) | (lin >> 3);
  const int qt = swz & 15;          // 16
  const int h  = (swz >> 4) & 15;   // 16
  const int b  = swz >> 8;          // 2
  const size_t bh = ((size_t)(b * NH + h)) * SEQ * DK;
  const unsigned short* Q  = Qb  + bh;
  const unsigned short* K  = Kb  + bh;
  const unsigned short* VT = VTb + bh;   // [64 d][2048 s]
  const int q0 = qt * 128;               // block covers q0..q0+127

  // K/V double-buffer (32 KB) overlaid with epilogue O-reduction buffer (34 KB)
  __shared__ __align__(16) unsigned char smem[2 * 64 * 68 * 4];
  unsigned short* Kl = (unsigned short*)smem;               // [2][64*64] swizzled
  unsigned short* Vl = (unsigned short*)(smem + 16384);     // [2][64*64] swizzled
  float* Ored = (float*)smem;                               // [2 ws][64 q][68] post-loop
  __shared__ float lbuf[2][4][128];                         // [ws][quad][q-local]

  // Q fragments (scaled by 1/8*log2e at projection): wave's 4 16-row groups
  bf16x8 qf[4][2];
#pragma unroll
  for (int qgi = 0; qgi < 4; ++qgi)
#pragma unroll
    for (int ks = 0; ks < 2; ++ks)
      qf[qgi][ks] = *(const bf16x8*)&Q[(size_t)(q0 + wq * 64 + qgi * 16 + x15) * DK + ks * 32 + quad * 8];

  f32x4 po[4][4] = {};
  float pol[4] = {0.f, 0.f, 0.f, 0.f};

  // staging maps (swizzled): K slot(s,dg)=s*8+(dg^(s&7)); V slot(d,sg)=d*8+(sg^(d&7))
  const int sK0 = tid >> 3,          sK1 = (tid + 256) >> 3;
  const int dgK0 = (tid & 7) ^ (sK0 & 7), dgK1 = (tid & 7) ^ (sK1 & 7);

  auto stageKV = [&](int buf, int s0) {
    g2l16(&Kl[buf * 4096 + tid * 8],         K + (size_t)(s0 + sK0) * DK + dgK0 * 8);
    g2l16(&Kl[buf * 4096 + (tid + 256) * 8], K + (size_t)(s0 + sK1) * DK + dgK1 * 8);
    g2l16(&Vl[buf * 4096 + tid * 8],         VT + (size_t)sK0 * SEQ + s0 + dgK0 * 8);
    g2l16(&Vl[buf * 4096 + (tid + 256) * 8], VT + (size_t)sK1 * SEQ + s0 + dgK1 * 8);
  };

  stageKV(0, 0);
  for (int s0 = 0; s0 < SEQ; s0 += 64) {
    const int cur = (s0 >> 6) & 1;
    __syncthreads();                 // drains last iter's prefetch; guards buf reuse
    if (s0 + 64 < SEQ) stageKV(cur ^ 1, s0 + 64);

    // this wave's K fragments: sh = ws*2 + shi
    bf16x8 kf[2][2];
#pragma unroll
    for (int shi = 0; shi < 2; ++shi) {
      const int sh = ws * 2 + shi;
      const int kbase = (sh * 16 + x15) * 8;
      kf[shi][0] = *(const bf16x8*)&Kl[cur * 4096 + (kbase + ((0 + quad) ^ (x15 & 7))) * 8];
      kf[shi][1] = *(const bf16x8*)&Kl[cur * 4096 + (kbase + ((4 + quad) ^ (x15 & 7))) * 8];
    }
    // this wave's V fragments
    bf16x4 vf[2][4];
#pragma unroll
    for (int shi = 0; shi < 2; ++shi)
#pragma unroll
      for (int nt = 0; nt < 4; ++nt) {
        const int d = nt * 16 + x15;
        const int sg = ((ws * 2 + shi) * 2 + (quad >> 1)) ^ (d & 7);
        vf[shi][nt] = *(const bf16x4*)&Vl[cur * 4096 + (d * 8 + sg) * 8 + (quad & 1) * 4];
      }

    __builtin_amdgcn_s_setprio(1);
#pragma unroll
    for (int shi = 0; shi < 2; ++shi) {
#pragma unroll
      for (int qgi = 0; qgi < 4; ++qgi) {
        f32x4 sacc = {};
        sacc = __builtin_amdgcn_mfma_f32_16x16x32_bf16(kf[shi][0], qf[qgi][0], sacc, 0, 0, 0);
        sacc = __builtin_amdgcn_mfma_f32_16x16x32_bf16(kf[shi][1], qf[qgi][1], sacc, 0, 0, 0);
        float p0 = __builtin_amdgcn_exp2f(sacc[0]);
        float p1 = __builtin_amdgcn_exp2f(sacc[1]);
        float p2 = __builtin_amdgcn_exp2f(sacc[2]);
        float p3 = __builtin_amdgcn_exp2f(sacc[3]);
        pol[qgi] += (p0 + p1) + (p2 + p3);     // in-lane row-sum partial (quad's 4 s)
        u32x2 uu;
        uu[0] = pkbf(p1, p0);
        uu[1] = pkbf(p3, p2);
        bf16x4 pf = __builtin_bit_cast(bf16x4, uu);
#pragma unroll
        for (int nt = 0; nt < 4; ++nt)
          po[qgi][nt] = MFMA16(vf[shi][nt], pf, po[qgi][nt]);
      }
    }
    __builtin_amdgcn_s_setprio(0);
  }

  // ---- epilogue: cross-quad l reduce + cross-ws O reduce via LDS ----
#pragma unroll
  for (int qgi = 0; qgi < 4; ++qgi)
    lbuf[ws][quad][wq * 64 + qgi * 16 + x15] = pol[qgi];
  __syncthreads();   // main-loop LDS traffic done; safe to overlay Ored; lbuf visible

  const int qq = tid >> 2;          // 0..63 (q-local within the round's half)
  const int d0 = (tid & 3) * 16;    // 0,16,32,48
#pragma unroll
  for (int rw = 0; rw < 2; ++rw) {
    if (wq == rw) {
      // write O^T partial: element (d = nt*16+quad*4+r, q = qgi*16+x15)
#pragma unroll
      for (int qgi = 0; qgi < 4; ++qgi)
#pragma unroll
        for (int nt = 0; nt < 4; ++nt)
          *(f32x4*)&Ored[(ws * 64 + qgi * 16 + x15) * 68 + nt * 16 + quad * 4] = po[qgi][nt];
    }
    __syncthreads();
    float ls = 0.f;
#pragma unroll
    for (int w2 = 0; w2 < 2; ++w2)
#pragma unroll
      for (int qd = 0; qd < 4; ++qd)
        ls += lbuf[w2][qd][rw * 64 + qq];
    const float inv = 1.0f / ls;
    const size_t orow = ((size_t)(b * SEQ + q0 + rw * 64 + qq)) * DM + h * DK + d0;
#pragma unroll
    for (int c = 0; c < 4; ++c) {
      f32x4 sa = *(const f32x4*)&Ored[(0 * 64 + qq) * 68 + d0 + c * 4];
      f32x4 sb = *(const f32x4*)&Ored[(1 * 64 + qq) * 68 + d0 + c * 4];
      us16x4 pk;
#pragma unroll
      for (int r = 0; r < 4; ++r) pk[r] = f2bf((sa[r] + sb[r]) * inv);
      *(us16x4*)&AO[orow + c * 4] = pk;
    }
    __syncthreads();  // before round 1 overwrites Ored
  }
}

extern "C" void kernel_launch(void* const* d_in, const int* in_sizes, int n_in,
                              void* d_out, int out_size, void* d_ws, size_t ws_size,
                              hipStream_t stream) {
  const float* q  = (const float*)d_in[0];
  const float* k  = (const float*)d_in[1];
  const float* v  = (const float*)d_in[2];
  const float* wq = (const float*)d_in[3];
  const float* bq = (const float*)d_in[4];
  const float* wk = (const float*)d_in[5];
  const float* bk = (const float*)d_in[6];
  const float* wv = (const float*)d_in[7];
  const float* bv = (const float*)d_in[8];
  const float* wo = (const float*)d_in[9];
  const float* bo = (const float*)d_in[10];
  float* out = (float*)d_out;

  unsigned short* ws = (unsigned short*)d_ws;
  unsigned short* Xq = ws;                               // 3*NX of X
  unsigned short* Wb = ws + (size_t)3 * NX;              // 4*NW of W
  unsigned short* Qb = ws + (size_t)3 * NX + 4 * NW;     // Q,K [B,H,S,DK]; V^T [B,H,DK,S]
  unsigned short* AO = Qb + (size_t)3 * NX;              // NX attn out

  // scale folded into Q: (1/sqrt(DK)) * log2(e)
  const float qscale = 0.125f * 1.4426950408889634f;

  cast_all<<<16384, 256, 0, stream>>>(q, k, v, wq, wk, wv, wo, ws);
  gemm_bt<0, 128><<<dim3(32, 8, 3), 256, 0, stream>>>(Xq, Wb, bq, bk, bv, Qb, nullptr, qscale);
  attn<<<dim3(16, 16, 2), 256, 0, stream>>>(Qb, Qb + (size_t)NX, Qb + (size_t)2 * NX, AO);
  gemm_bt<1, 64><<<dim3(64, 8, 1), 256, 0, stream>>>(AO, Wb + (size_t)3 * NW, bo, bo, bo,
                                                     nullptr, out, 1.0f);
}